// Round 6
// baseline (675.705 us; speedup 1.0000x reference)
//
#include <hip/hip_runtime.h>
#include <hip/hip_bf16.h>
#include <math.h>

typedef __attribute__((ext_vector_type(4))) float f32x4;
typedef __attribute__((ext_vector_type(16))) float f32x16;
typedef __attribute__((ext_vector_type(8))) int i32x8;
typedef __attribute__((ext_vector_type(4))) int i32x4;

#define TEMP_INV 14.2857142857142857f   // 1/0.07
#define UNIT_SCALE 0x7f7f7f7f           // E8M0 127 -> x1.0 exact (verified)

union frag32 {
  i32x8 v8;
  struct { i32x4 lo; i32x4 hi; } s;
};

// ---- async global->LDS, 16B per lane
static __device__ inline void async16(const void* g, void* l) {
  __builtin_amdgcn_global_load_lds(
      (const __attribute__((address_space(1))) unsigned int*)g,
      (__attribute__((address_space(3))) unsigned int*)l,
      16, 0, 0);
}

// ============================================================
// Fragment-major fp8 format, piece-split (verified absmax=0, R4/R5):
//   panel p = 32 rows, k-step s = 64 K-bytes. record(p,s) = 2 KB at
//   (p*16+s)*2048. Lane l holds row p*32+(l&31), k-bytes
//   s*64+(l>>5)*32..+31, as TWO 16B pieces: lo at rec+l*16,
//   hi at rec+1024+l*16. For a 4-byte f32-group at row-byte o:
//   int idx = (p*16 + (o>>6))*512 + ((o>>4)&1)*256
//           + (((o>>5)&1)*32 + (row&31))*4 + ((o>>2)&3)
//   (same algebra as the verified R4 EMIT formula).
// ============================================================

// ============================================================
// Kernel 1: L2-normalize rows (D=1024) -> fp8 fragment-major.
// R6: one block = one 32-row panel (1024 thr, 32 thr/row). Pack the
// panel's 16 records (32 KB) in LDS, then copy out LINEARLY (R5's
// scattered 16B global writes were ~+10 us). Thread (r,c): r=tid>>5,
// c=tid&31; reads float4 f = c+32i (i=0..7) of its row (coalesced),
// 5-step width-32 shfl reduce, quantize, LDS-scatter (int granules),
// barrier, int4 linear copy-out.
// ============================================================
__global__ __launch_bounds__(1024) void normalize_rows(
    const float* __restrict__ a, const float* __restrict__ b,
    int* __restrict__ oa, int* __restrict__ ob,
    float* __restrict__ pos_acc, float* __restrict__ neg_acc,
    int N, int D) {
  __shared__ __align__(16) int sPk[8192];  // 32 KB: 16 records x 2 KB

  const int blk = blockIdx.x;          // 0..511
  const bool isA = blk < 256;
  const int p = isA ? blk : blk - 256; // panel index within its matrix
  const float* src = (isA ? a : b) + (size_t)p * 32 * D;
  int* out = isA ? oa : ob;

  const int tid = threadIdx.x;
  const int r = tid >> 5;   // 0..31 row within panel
  const int c = tid & 31;   // 0..31 chunk within row

  if (isA && c == 0) {
    const int row = p * 32 + r;
    pos_acc[row] = 0.f;
    neg_acc[row] = 0.f;
  }

  const float4* inr = (const float4*)(src + (size_t)r * D);
  float4 v[8];
#pragma unroll
  for (int i = 0; i < 8; i++) v[i] = inr[c + 32 * i];

  float ss = 0.f;
#pragma unroll
  for (int i = 0; i < 8; i++)
    ss += v[i].x * v[i].x + v[i].y * v[i].y + v[i].z * v[i].z + v[i].w * v[i].w;
#pragma unroll
  for (int m = 16; m >= 1; m >>= 1) ss += __shfl_xor(ss, m, 32);
  const float inv = 1.0f / fmaxf(sqrtf(ss), 1e-12f);

  // quantize + LDS scatter at verified fragment-major offsets
#pragma unroll
  for (int i = 0; i < 8; i++) {
    int rp = __builtin_amdgcn_cvt_pk_fp8_f32(v[i].x * inv, v[i].y * inv, 0, false);
    rp = __builtin_amdgcn_cvt_pk_fp8_f32(v[i].z * inv, v[i].w * inv, rp, true);
    const int f = c + 32 * i;  // 4-byte group index (o = 4f)
    const int idx = (f >> 4) * 512 + ((f >> 2) & 1) * 256 +
                    (((f >> 3) & 1) * 32 + r) * 4 + (f & 3);
    sPk[idx] = rp;
  }
  __syncthreads();

  // linear copy-out: 32 KB = 2048 int4
  const int4* sp4 = (const int4*)sPk;
  int4* op4 = (int4*)(out + (size_t)p * 8192);
#pragma unroll
  for (int j = 0; j < 2; j++) op4[tid + j * 1024] = sp4[tid + j * 1024];
}

// ============================================================
// Kernel 2: fused MX-fp8 GEMM + exp epilogue.
// R6: counted-vmcnt triple-buffer INSIDE the multi-resident envelope.
//  * tile 128x128, 4 waves 2x2, wave 64x64 (acc[2][2] 32x32x64 MFMA)
//  * BK=64 (one record-step): per K-tile stage 16 KB (4 async16/thr)
//  * sT[3][16KB] = 48 KB -> 3 blocks/CU; launch_bounds(256,3)
//  * stage tile t+2 at iter t; RAW s_barrier per tile; s_waitcnt
//    vmcnt(4) at the boundary (waits tile t+1 only, issued a full
//    K-tile earlier -> latency hidden; NEVER vmcnt(0) in-loop).
//  * fragment-major: linear staging, stride-16 conflict-free ds_read.
// Race audit: wave's ds_reads of buf X complete before its MFMAs
// (compiler lgkmcnt) which precede its barrier arrival; the iter-t
// STAGE overwrites the buffer read at iter t-1, behind that barrier.
// ============================================================
__global__ __launch_bounds__(256, 3) void infonce_gemm(
    const unsigned char* __restrict__ A, const unsigned char* __restrict__ B,
    const int* __restrict__ la, const int* __restrict__ lb,
    float* __restrict__ pos_acc, float* __restrict__ neg_acc) {
  __shared__ __align__(16) unsigned char sT[3][16384];  // A 8KB | B 8KB

  const int tid = threadIdx.x;
  const int lane = tid & 63;
  const int wave = tid >> 6;  // 0..3
  const int wm = wave >> 1;   // 0..1 (M half: 64 rows)
  const int wn = wave & 1;    // 0..1 (N half: 64 cols)

  // grid 4096 = 64 by x 64 bx; bijective XCD rectangle swizzle
  const int bid = blockIdx.x;
  const int xcd = bid & 7;
  const int local = bid >> 3;              // 0..511
  const int by = xcd * 8 + (local & 7);    // 0..63
  const int bx = local >> 3;               // 0..63
  const int row0 = by * 128;
  const int col0 = bx * 128;

  // staging: tid covers record u2=tid>>7 of each pair, inner (tid&127)*16
  const int u2 = tid >> 7;
  const int inner = (tid & 127) * 16;
  const unsigned char* gA = A + ((size_t)(by * 4 + u2)) * 32768 + inner;
  const unsigned char* gB = B + ((size_t)(bx * 4 + u2)) * 32768 + inner;

  f32x16 acc[2][2] = {};

#define STAGE(bf, s)                                                     \
  do {                                                                   \
    async16(gA + (size_t)(s)*2048, &sT[bf][tid * 16]);                   \
    async16(gA + 2 * 32768 + (size_t)(s)*2048, &sT[bf][4096 + tid * 16]);\
    async16(gB + (size_t)(s)*2048, &sT[bf][8192 + tid * 16]);            \
    async16(gB + 2 * 32768 + (size_t)(s)*2048,                           \
            &sT[bf][12288 + tid * 16]);                                  \
  } while (0)

// lane's 32B fragment: lo + hi piece, both stride-16 (conflict-free)
#define LD32(dst, base, off)                                        \
  do {                                                              \
    frag32 _f;                                                      \
    _f.s.lo = *(const i32x4*)((base) + (off));                      \
    _f.s.hi = *(const i32x4*)((base) + (off) + 1024);               \
    dst = _f.v8;                                                    \
  } while (0)

#define MFMA(ci, a_, b_)                                            \
  ci = __builtin_amdgcn_mfma_scale_f32_32x32x64_f8f6f4(             \
      a_, b_, ci, 0, 0, 0, UNIT_SCALE, 0, UNIT_SCALE)

  const int lofs = lane * 16;
  const int aoff0 = (wm * 2 + 0) * 2048 + lofs;
  const int aoff1 = (wm * 2 + 1) * 2048 + lofs;
  const int boff0 = 8192 + (wn * 2 + 0) * 2048 + lofs;
  const int boff1 = 8192 + (wn * 2 + 1) * 2048 + lofs;

  // prologue: tiles 0,1 in flight; wait tile 0 (4 newest = tile 1)
  STAGE(0, 0);
  STAGE(1, 1);
  asm volatile("s_waitcnt vmcnt(4)" ::: "memory");
  __builtin_amdgcn_s_barrier();

#pragma unroll
  for (int t = 0; t < 16; ++t) {
    const int cur = t % 3;
    if (t < 14) STAGE((t + 2) % 3, t + 2);
    const unsigned char* cb = sT[cur];
    i32x8 a0, a1, b0, b1;
    LD32(a0, cb, aoff0);
    LD32(a1, cb, aoff1);
    LD32(b0, cb, boff0);
    LD32(b1, cb, boff1);
    __builtin_amdgcn_s_setprio(1);
    MFMA(acc[0][0], a0, b0);
    MFMA(acc[0][1], a0, b1);
    MFMA(acc[1][0], a1, b0);
    MFMA(acc[1][1], a1, b1);
    __builtin_amdgcn_s_setprio(0);
    if (t < 14)
      asm volatile("s_waitcnt vmcnt(4)" ::: "memory");  // tile t+1 resident
    else
      asm volatile("s_waitcnt vmcnt(0)" ::: "memory");  // drain tail
    __builtin_amdgcn_s_barrier();
  }

  // ---- epilogue: 32x32 C/D layout col=lane&31,
  //      row=(reg&3)+8*(reg>>2)+4*(lane>>5)  (verified, absmax 0)
  const int l31 = lane & 31;
  const int hi = lane >> 5;
  const int lb0 = lb[col0 + wn * 64 + l31];
  const int lb1 = lb[col0 + wn * 64 + 32 + l31];
  const int rbase = row0 + wm * 64 + 4 * hi;

#pragma unroll
  for (int mi = 0; mi < 2; mi++) {
#pragma unroll
    for (int r = 0; r < 16; r++) {
      const int row = rbase + mi * 32 + (r & 3) + 8 * (r >> 2);
      const int lav = la[row];
      float s0 = acc[mi][0][r] * TEMP_INV;
      float s1 = acc[mi][1][r] * TEMP_INV;
      s0 = fminf(fmaxf(s0, -50.f), 50.f);
      s1 = fminf(fmaxf(s1, -50.f), 50.f);
      const float e0 = __expf(s0);
      const float e1 = __expf(s1);
      float sneg = e0 + e1;
      float spos = (lav == lb0 ? e0 : 0.f) + (lav == lb1 ? e1 : 0.f);
#pragma unroll
      for (int m = 16; m >= 1; m >>= 1) {
        sneg += __shfl_xor(sneg, m, 32);
        spos += __shfl_xor(spos, m, 32);
      }
      if (l31 == 0) {
        atomicAdd(&neg_acc[row], sneg);
        atomicAdd(&pos_acc[row], spos);
      }
    }
  }
}

// ============================================================
// Kernel 3: loss = mean( log(neg) - log(max(pos,1e-8)) ) (unchanged)
// ============================================================
__global__ __launch_bounds__(1024) void final_reduce(
    const float* __restrict__ pos, const float* __restrict__ neg,
    float* __restrict__ out, int N) {
  double local = 0.0;
  const int t = threadIdx.x;
  for (int i = t; i < N / 4; i += 1024) {
    const float4 p4 = ((const float4*)pos)[i];
    const float4 n4 = ((const float4*)neg)[i];
    local += (double)(logf(n4.x) - logf(fmaxf(p4.x, 1e-8f)));
    local += (double)(logf(n4.y) - logf(fmaxf(p4.y, 1e-8f)));
    local += (double)(logf(n4.z) - logf(fmaxf(p4.z, 1e-8f)));
    local += (double)(logf(n4.w) - logf(fmaxf(p4.w, 1e-8f)));
  }
#pragma unroll
  for (int m = 32; m >= 1; m >>= 1) local += __shfl_xor(local, m, 64);
  __shared__ double wsum[16];
  const int wave = t >> 6, lane = t & 63;
  if (lane == 0) wsum[wave] = local;
  __syncthreads();
  if (t == 0) {
    double tot = 0.0;
#pragma unroll
    for (int w = 0; w < 16; w++) tot += wsum[w];
    out[0] = (float)(tot / (double)N);
  }
}

extern "C" void kernel_launch(void* const* d_in, const int* in_sizes, int n_in,
                              void* d_out, int out_size, void* d_ws, size_t ws_size,
                              hipStream_t stream) {
  const float* fa = (const float*)d_in[0];
  const float* fb = (const float*)d_in[1];
  const int* la = (const int*)d_in[2];
  const int* lb = (const int*)d_in[3];

  const int D = 1024;
  const int N = in_sizes[0] / D;  // 8192
  const int M = in_sizes[1] / D;  // 8192

  unsigned char* nA = (unsigned char*)d_ws;
  unsigned char* nB = nA + (size_t)N * D;
  float* pos = (float*)(nB + (size_t)M * D);
  float* neg = pos + N;

  normalize_rows<<<512, 1024, 0, stream>>>(fa, fb, (int*)nA, (int*)nB, pos,
                                           neg, N, D);

  infonce_gemm<<<4096, 256, 0, stream>>>(nA, nB, la, lb, pos, neg);

  final_reduce<<<1, 1024, 0, stream>>>(pos, neg, (float*)d_out, N);
}

// Round 7
// 234.558 us; speedup vs baseline: 2.8808x; 2.8808x over previous
//
#include <hip/hip_runtime.h>
#include <hip/hip_bf16.h>
#include <math.h>

typedef __attribute__((ext_vector_type(4))) float f32x4;
typedef __attribute__((ext_vector_type(16))) float f32x16;
typedef __attribute__((ext_vector_type(8))) int i32x8;
typedef __attribute__((ext_vector_type(4))) int i32x4;

#define TEMP_INV 14.2857142857142857f   // 1/0.07
#define UNIT_SCALE 0x7f7f7f7f           // E8M0 127 -> x1.0 exact (verified)

union frag32 {
  i32x8 v8;
  struct { i32x4 lo; i32x4 hi; } s;
};

// ---- async global->LDS, 16B per lane
static __device__ inline void async16(const void* g, void* l) {
  __builtin_amdgcn_global_load_lds(
      (const __attribute__((address_space(1))) unsigned int*)g,
      (__attribute__((address_space(3))) unsigned int*)l,
      16, 0, 0);
}

// ============================================================
// Fragment-major fp8 format, piece-split (verified absmax=0, R4-R6):
//   panel p = 32 rows, k-step s = 64 K-bytes. record(p,s) = 2 KB at
//   (p*16+s)*2048. Lane l holds row p*32+(l&31), k-bytes
//   s*64+(l>>5)*32..+31, as TWO 16B pieces: lo at rec+l*16,
//   hi at rec+1024+l*16.
// ============================================================

// ============================================================
// Kernel 1: L2-normalize rows (D=1024) -> fp8 fragment-major.
// (R6 version, kept: panel-per-block LDS pack + LINEAR copy-out.)
// ============================================================
__global__ __launch_bounds__(1024) void normalize_rows(
    const float* __restrict__ a, const float* __restrict__ b,
    int* __restrict__ oa, int* __restrict__ ob,
    float* __restrict__ pos_acc, float* __restrict__ neg_acc,
    int N, int D) {
  __shared__ __align__(16) int sPk[8192];  // 32 KB: 16 records x 2 KB

  const int blk = blockIdx.x;          // 0..511
  const bool isA = blk < 256;
  const int p = isA ? blk : blk - 256; // panel index within its matrix
  const float* src = (isA ? a : b) + (size_t)p * 32 * D;
  int* out = isA ? oa : ob;

  const int tid = threadIdx.x;
  const int r = tid >> 5;   // 0..31 row within panel
  const int c = tid & 31;   // 0..31 chunk within row

  if (isA && c == 0) {
    const int row = p * 32 + r;
    pos_acc[row] = 0.f;
    neg_acc[row] = 0.f;
  }

  const float4* inr = (const float4*)(src + (size_t)r * D);
  float4 v[8];
#pragma unroll
  for (int i = 0; i < 8; i++) v[i] = inr[c + 32 * i];

  float ss = 0.f;
#pragma unroll
  for (int i = 0; i < 8; i++)
    ss += v[i].x * v[i].x + v[i].y * v[i].y + v[i].z * v[i].z + v[i].w * v[i].w;
#pragma unroll
  for (int m = 16; m >= 1; m >>= 1) ss += __shfl_xor(ss, m, 32);
  const float inv = 1.0f / fmaxf(sqrtf(ss), 1e-12f);

#pragma unroll
  for (int i = 0; i < 8; i++) {
    int rp = __builtin_amdgcn_cvt_pk_fp8_f32(v[i].x * inv, v[i].y * inv, 0, false);
    rp = __builtin_amdgcn_cvt_pk_fp8_f32(v[i].z * inv, v[i].w * inv, rp, true);
    const int f = c + 32 * i;  // 4-byte group index (o = 4f)
    const int idx = (f >> 4) * 512 + ((f >> 2) & 1) * 256 +
                    (((f >> 3) & 1) * 32 + r) * 4 + (f & 3);
    sPk[idx] = rp;
  }
  __syncthreads();

  const int4* sp4 = (const int4*)sPk;
  int4* op4 = (int4*)(out + (size_t)p * 8192);
#pragma unroll
  for (int j = 0; j < 2; j++) op4[tid + j * 1024] = sp4[tid + j * 1024];
}

// ============================================================
// Kernel 2: fused MX-fp8 GEMM + exp epilogue.
// R7 = R5 (best: 138 us) + ONE change: half-tile (BK=64) ping-pong
// with STAGE issued BEFORE the current half's compute.
//  * same LDS total (2 x 16 KB = 32 KB -> ~3+ blocks/CU, R5's asset)
//  * same barrier count (16 __syncthreads), same bytes/step economics
//  * delta: each barrier's vmcnt(0) drain now lands ~300-400 cyc
//    after stage issue (hidden behind 8 ds_read_b128 + 4 MFMA)
//    instead of 0 cyc (R5 exposed the full stage latency every tile).
//  * NO inline asm / setprio in the loop (R6 post-mortem: asm grafts
//    in the hot loop caused frag spill -> 2 GB scratch traffic).
// Race audit: iter s stages into buf^1, reads buf (disjoint). The
// end-of-iter __syncthreads drains staging (next iter's read source)
// and fences this iter's reads before iter s+1 overwrites buf.
// ============================================================
__global__ __launch_bounds__(256, 3) void infonce_gemm(
    const unsigned char* __restrict__ A, const unsigned char* __restrict__ B,
    const int* __restrict__ la, const int* __restrict__ lb,
    float* __restrict__ pos_acc, float* __restrict__ neg_acc) {
  __shared__ __align__(16) unsigned char sH[2][16384];  // A 8KB | B 8KB

  const int tid = threadIdx.x;
  const int lane = tid & 63;
  const int wave = tid >> 6;  // 0..3
  const int wm = wave >> 1;   // 0..1 (M half: 64 rows)
  const int wn = wave & 1;    // 0..1 (N half: 64 cols)

  // grid 4096 = 64 by x 64 bx; bijective XCD rectangle swizzle
  const int bid = blockIdx.x;
  const int xcd = bid & 7;
  const int local = bid >> 3;              // 0..511
  const int by = xcd * 8 + (local & 7);    // 0..63
  const int bx = local >> 3;               // 0..63
  const int row0 = by * 128;
  const int col0 = bx * 128;

  // staging: tid covers record pair u2=tid>>7, inner (tid&127)*16
  const int u2 = tid >> 7;
  const int inner = (tid & 127) * 16;
  const unsigned char* gA = A + ((size_t)(by * 4 + u2)) * 32768 + inner;
  const unsigned char* gB = B + ((size_t)(bx * 4 + u2)) * 32768 + inner;

  f32x16 acc[2][2] = {};

// stage half-step s (one 2KB record per panel; A 8KB + B 8KB)
#define STAGE(bf, s)                                                     \
  do {                                                                   \
    async16(gA + (size_t)(s)*2048, &sH[bf][tid * 16]);                   \
    async16(gA + 2 * 32768 + (size_t)(s)*2048, &sH[bf][4096 + tid * 16]);\
    async16(gB + (size_t)(s)*2048, &sH[bf][8192 + tid * 16]);            \
    async16(gB + 2 * 32768 + (size_t)(s)*2048,                           \
            &sH[bf][12288 + tid * 16]);                                  \
  } while (0)

// lane's 32B fragment: lo + hi piece, both stride-16 (conflict-free)
#define LD32(dst, base, off)                                        \
  do {                                                              \
    frag32 _f;                                                      \
    _f.s.lo = *(const i32x4*)((base) + (off));                      \
    _f.s.hi = *(const i32x4*)((base) + (off) + 1024);               \
    dst = _f.v8;                                                    \
  } while (0)

#define MFMA(ci, a_, b_)                                            \
  ci = __builtin_amdgcn_mfma_scale_f32_32x32x64_f8f6f4(             \
      a_, b_, ci, 0, 0, 0, UNIT_SCALE, 0, UNIT_SCALE)

  const int lofs = lane * 16;
  const int aoff0 = (wm * 2 + 0) * 2048 + lofs;
  const int aoff1 = (wm * 2 + 1) * 2048 + lofs;
  const int boff0 = 8192 + (wn * 2 + 0) * 2048 + lofs;
  const int boff1 = 8192 + (wn * 2 + 1) * 2048 + lofs;

  STAGE(0, 0);
  __syncthreads();  // prologue drain: half 0 resident

#pragma unroll 1
  for (int s = 0; s < 16; ++s) {
    const int buf = s & 1;
    if (s < 15) STAGE(buf ^ 1, s + 1);  // issue BEFORE compute
    const unsigned char* cb = sH[buf];
    i32x8 a0, a1, b0, b1;
    LD32(a0, cb, aoff0);
    LD32(a1, cb, aoff1);
    LD32(b0, cb, boff0);
    LD32(b1, cb, boff1);
    MFMA(acc[0][0], a0, b0);
    MFMA(acc[0][1], a0, b1);
    MFMA(acc[1][0], a1, b0);
    MFMA(acc[1][1], a1, b1);
    __syncthreads();  // drain staged half s+1; fence reads of buf
  }

  // ---- epilogue: 32x32 C/D layout col=lane&31,
  //      row=(reg&3)+8*(reg>>2)+4*(lane>>5)  (verified, absmax 0)
  const int l31 = lane & 31;
  const int hi = lane >> 5;
  const int lb0 = lb[col0 + wn * 64 + l31];
  const int lb1 = lb[col0 + wn * 64 + 32 + l31];
  const int rbase = row0 + wm * 64 + 4 * hi;

#pragma unroll
  for (int mi = 0; mi < 2; mi++) {
#pragma unroll
    for (int r = 0; r < 16; r++) {
      const int row = rbase + mi * 32 + (r & 3) + 8 * (r >> 2);
      const int lav = la[row];
      float s0 = acc[mi][0][r] * TEMP_INV;
      float s1 = acc[mi][1][r] * TEMP_INV;
      s0 = fminf(fmaxf(s0, -50.f), 50.f);
      s1 = fminf(fmaxf(s1, -50.f), 50.f);
      const float e0 = __expf(s0);
      const float e1 = __expf(s1);
      float sneg = e0 + e1;
      float spos = (lav == lb0 ? e0 : 0.f) + (lav == lb1 ? e1 : 0.f);
#pragma unroll
      for (int m = 16; m >= 1; m >>= 1) {
        sneg += __shfl_xor(sneg, m, 32);
        spos += __shfl_xor(spos, m, 32);
      }
      if (l31 == 0) {
        atomicAdd(&neg_acc[row], sneg);
        atomicAdd(&pos_acc[row], spos);
      }
    }
  }
}

// ============================================================
// Kernel 3: loss = mean( log(neg) - log(max(pos,1e-8)) ) (unchanged)
// ============================================================
__global__ __launch_bounds__(1024) void final_reduce(
    const float* __restrict__ pos, const float* __restrict__ neg,
    float* __restrict__ out, int N) {
  double local = 0.0;
  const int t = threadIdx.x;
  for (int i = t; i < N / 4; i += 1024) {
    const float4 p4 = ((const float4*)pos)[i];
    const float4 n4 = ((const float4*)neg)[i];
    local += (double)(logf(n4.x) - logf(fmaxf(p4.x, 1e-8f)));
    local += (double)(logf(n4.y) - logf(fmaxf(p4.y, 1e-8f)));
    local += (double)(logf(n4.z) - logf(fmaxf(p4.z, 1e-8f)));
    local += (double)(logf(n4.w) - logf(fmaxf(p4.w, 1e-8f)));
  }
#pragma unroll
  for (int m = 32; m >= 1; m >>= 1) local += __shfl_xor(local, m, 64);
  __shared__ double wsum[16];
  const int wave = t >> 6, lane = t & 63;
  if (lane == 0) wsum[wave] = local;
  __syncthreads();
  if (t == 0) {
    double tot = 0.0;
#pragma unroll
    for (int w = 0; w < 16; w++) tot += wsum[w];
    out[0] = (float)(tot / (double)N);
  }
}

extern "C" void kernel_launch(void* const* d_in, const int* in_sizes, int n_in,
                              void* d_out, int out_size, void* d_ws, size_t ws_size,
                              hipStream_t stream) {
  const float* fa = (const float*)d_in[0];
  const float* fb = (const float*)d_in[1];
  const int* la = (const int*)d_in[2];
  const int* lb = (const int*)d_in[3];

  const int D = 1024;
  const int N = in_sizes[0] / D;  // 8192
  const int M = in_sizes[1] / D;  // 8192

  unsigned char* nA = (unsigned char*)d_ws;
  unsigned char* nB = nA + (size_t)N * D;
  float* pos = (float*)(nB + (size_t)M * D);
  float* neg = pos + N;

  normalize_rows<<<512, 1024, 0, stream>>>(fa, fb, (int*)nA, (int*)nB, pos,
                                           neg, N, D);

  infonce_gemm<<<4096, 256, 0, stream>>>(nA, nB, la, lb, pos, neg);

  final_reduce<<<1, 1024, 0, stream>>>(pos, neg, (float*)d_out, N);
}